// Round 17
// baseline (132.453 us; speedup 1.0000x reference)
//
#include <hip/hip_runtime.h>
#include <math.h>

#define B_ 4
#define N_ 4096
#define D_ 128
#define NS_ 16
#define NT_ 64
#define SCALE_ 0.08838834764831843f
#define EPS_ 1e-10f

typedef __attribute__((ext_vector_type(8))) short bf16x8;
typedef __attribute__((ext_vector_type(4))) float f32x4;
union U8 { uint4 q; bf16x8 v; };

// workspace offsets (in 4-byte words)
#define OFF_K      ((size_t)0)                    /* bf16 [B*N][128] = B*N*64 words */
#define OFF_V      (OFF_K + (size_t)B_*N_*64)
#define OFF_WCP    (OFF_V + (size_t)B_*N_*64)     /* uint4 [32][512] octo-packed GRU */
#define OFF_M1P    (OFF_WCP + 64*512*2)           /* uint4 [16][512] */
#define OFF_M2P    (OFF_M1P + 32*512*2)           /* uint4 [64][128] */
#define OFF_WQP    (OFF_M2P + 128*128*2)          /* uint4 [16][128] */
#define OFF_O1P    (OFF_WQP + 32*128*2)           /* uint4 [32][1024] */
#define OFF_O2P    (OFF_O1P + (size_t)64*1024*2)  /* uint4 [128][128] */
#define OFF_MU     (OFF_O2P + 256*128*2)
#define OFF_WCOEF  (OFF_MU + (size_t)B_*NS_*128)  /* [b][16][128][2] */
#define OFF_C      (OFF_WCOEF + (size_t)B_*128*32)
#define OFF_PART   (OFF_C + 64)
#define OFF_ATTNU  (OFF_PART + (size_t)B_*NT_*NS_*260)

// slot scratch offsets (floats)
#define S_ZS    0
#define S_S2    256
#define S_UU    384
#define S_H2    512
#define S_A1S   640
#define S_SNEW  1152
#define S_QM    1408
#define S_QL    1536
#define S_RED   1664
#define S_P1    2688
#define S_TOT   3712

__device__ __forceinline__ float bf_lo(unsigned p) { return __uint_as_float(p << 16); }
__device__ __forceinline__ float bf_hi(unsigned p) { return __uint_as_float(p & 0xffff0000u); }
__device__ __forceinline__ unsigned packbf(float lo, float hi) {
  unsigned ul = __float_as_uint(lo), uh = __float_as_uint(hi);
  ul = (ul + 0x7fffu + ((ul >> 16) & 1u)) >> 16;
  uh = (uh + 0x7fffu + ((uh >> 16) & 1u)) >> 16;
  return (ul & 0xffffu) | (uh << 16);
}

__device__ __forceinline__ float waveRed1(float a) {
  #pragma unroll
  for (int off = 32; off > 0; off >>= 1) a += __shfl_down(a, off, 64);
  return a;
}
__device__ __forceinline__ float2 waveRed2(float a, float b) {
  #pragma unroll
  for (int off = 32; off > 0; off >>= 1) {
    a += __shfl_down(a, off, 64);
    b += __shfl_down(b, off, 64);
  }
  return make_float2(a, b);
}

// octo-FMA helper: 8 bf16 weights (uint4) x 8 activations
__device__ __forceinline__ void oct_fma(const uint4& p, const float* s,
    float& a0, float& a1, float& a2, float& a3) {
  a0 = fmaf(s[0], bf_lo(p.x), a0);
  a1 = fmaf(s[1], bf_hi(p.x), a1);
  a2 = fmaf(s[2], bf_lo(p.y), a2);
  a3 = fmaf(s[3], bf_hi(p.y), a3);
  a0 = fmaf(s[4], bf_lo(p.z), a0);
  a1 = fmaf(s[5], bf_hi(p.z), a1);
  a2 = fmaf(s[6], bf_lo(p.w), a2);
  a3 = fmaf(s[7], bf_hi(p.w), a3);
}

// packed-weight + bias bundle
struct SW {
  const unsigned* wcP;
  const unsigned* m1P;
  const unsigned* m2P;
  const unsigned* wqP;
  const float* bih; const float* bhh;
  const float* mb1; const float* mb2;
  const float* gmu; const float* bmu;
  const float* gsl; const float* bsl;
};
// raw f32 weights
struct RW {
  const float* Wq; const float* Wk; const float* Wv;
  const float* Wih; const float* Whh;
  const float* mW1; const float* mW2;
  const float* oW1; const float* oW2;
};

// shared merge for slot tails: qpart in S_P1[4][256] -> wcoef/cbuf
__device__ __forceinline__ void tailMerge(float* sl, int b, int i, int tid,
    float* wcoef, float* cbuf) {
  float* red = sl + S_RED;
  if (tid < 256) {
    float q = sl[S_P1 + tid] + sl[S_P1 + 256 + tid] + sl[S_P1 + 512 + tid] + sl[S_P1 + 768 + tid];
    if (tid < 128) sl[S_QM + tid] = q; else sl[S_QL + (tid - 128)] = q;
  }
  __syncthreads();
  if (tid < 128) {
    float iv = expf(-2.f * sl[S_QL + tid]);
    float a1 = SCALE_ * iv;
    float a2 = -2.f * SCALE_ * iv * sl[S_QM + tid];
    float* wrow = &wcoef[(((size_t)b * 16 + i) * 128 + tid) * 2];
    wrow[0] = a2;
    wrow[1] = a1;
    float cp = SCALE_ * iv * sl[S_QM + tid] * sl[S_QM + tid];
    float r = waveRed1(cp);
    if ((tid & 63) == 0) red[16 + (tid >> 6)] = r;
  }
  __syncthreads();
  if (tid == 0) cbuf[b * NS_ + i] = red[16] + red[17];
}

// packed-wq tail (rK): sl[S_A1S..+255] = LN'd slot row
__device__ __forceinline__ void slotTail1024(float* sl, int b, int i, int tid,
    const unsigned* __restrict__ wqPu, float* wcoef, float* cbuf) {
  {
    int rest = tid & 255, kg = tid >> 8;
    int wh = rest >> 7, o = rest & 127;
    const uint4* wq = (const uint4*)wqPu + (size_t)(kg * 4) * 128 + o;
    const float* s = sl + S_A1S + wh * 128 + kg * 32;
    float a0 = 0.f, a1 = 0.f, a2 = 0.f, a3 = 0.f;
    #pragma unroll
    for (int r = 0; r < 4; ++r)
      oct_fma(wq[r * 128], s + 8 * r, a0, a1, a2, a3);
    sl[S_P1 + kg * 256 + rest] = (a0 + a1) + (a2 + a3);
  }
  __syncthreads();
  tailMerge(sl, b, i, tid, wcoef, cbuf);
}

// f32 raw-Wq tail (kvK slot-prep only; wqP not yet written in this launch)
__device__ __forceinline__ void slotTailF(float* sl, int b, int i, int tid,
    const float* __restrict__ Wq, float* wcoef, float* cbuf) {
  {
    int rest = tid & 255, kg = tid >> 8;
    int wh = rest >> 7, o = rest & 127;
    const float4* wr = (const float4*)&Wq[(size_t)o * 128 + kg * 32];
    const float* s = sl + S_A1S + wh * 128 + kg * 32;
    float a0 = 0.f, a1 = 0.f, a2 = 0.f, a3 = 0.f;
    #pragma unroll
    for (int r = 0; r < 8; ++r) {
      float4 wv = wr[r];
      a0 = fmaf(s[4 * r],     wv.x, a0);
      a1 = fmaf(s[4 * r + 1], wv.y, a1);
      a2 = fmaf(s[4 * r + 2], wv.z, a2);
      a3 = fmaf(s[4 * r + 3], wv.w, a3);
    }
    sl[S_P1 + kg * 256 + rest] = (a0 + a1) + (a2 + a3);
  }
  __syncthreads();
  tailMerge(sl, b, i, tid, wcoef, cbuf);
}

// 1024-thread slot update. FINAL=0: full incl. next-step prep. FINAL=1: stop with snew in LDS.
template <int FINAL>
__device__ void slotUpdateT(float* sl, int b, int i, int tid,
    const float* __restrict__ part, float* mu, float* wcoef, float* cbuf, SW w) {
  float* red = sl + S_RED;
  size_t pbase = ((size_t)(b * NT_) * NS_ + i) * 260;
  const size_t pstr = (size_t)NS_ * 260;
  {
    int g = tid >> 8, e = tid & 255;
    float s = 0.f;
    #pragma unroll 16
    for (int t = 0; t < 16; ++t) s += part[pbase + (size_t)(g * 16 + t) * pstr + e];
    sl[S_P1 + g * 256 + e] = s;
  }
  if (tid < 64) {
    float rtv = waveRed1(part[pbase + (size_t)tid * pstr + 256]);
    if (tid == 0) red[0] = rtv;
  }
  __syncthreads();  // B1
  float rt = red[0];
  if (tid < 256) {
    float s = sl[S_P1 + tid] + sl[S_P1 + 256 + tid] + sl[S_P1 + 512 + tid] + sl[S_P1 + 768 + tid];
    if (tid < 128) sl[S_ZS + tid] = s / rt; else sl[S_S2 + tid - 128] = s / rt;
  } else if (tid < 384) {
    sl[S_ZS + tid - 128] = mu[(size_t)(b * NS_ + i) * 128 + (tid - 256)];
  }
  __syncthreads();  // B2
  // GRU matvec: 512 outputs, 2-way K-split, octo-packed
  {
    int q = tid & 511, kg = tid >> 9;
    const uint4* wcol = (const uint4*)w.wcP + (size_t)(kg * 16) * 512 + q;
    const float* xz = sl + S_ZS + kg * 128;
    float a0 = 0.f, a1 = 0.f, a2 = 0.f, a3 = 0.f;
    #pragma unroll
    for (int r = 0; r < 16; ++r)
      oct_fma(wcol[r * 512], xz + 8 * r, a0, a1, a2, a3);
    sl[S_P1 + kg * 512 + q] = (a0 + a1) + (a2 + a3);
  }
  __syncthreads();  // B3
  float uu_reg = 0.f;
  if (tid < 128) {
    float o_r = sl[S_P1 + tid] + sl[S_P1 + 512 + tid];
    float o_z = sl[S_P1 + 128 + tid] + sl[S_P1 + 640 + tid];
    float o_n = sl[S_P1 + 256 + tid] + sl[S_P1 + 768 + tid];
    float o_g = sl[S_P1 + 384 + tid] + sl[S_P1 + 896 + tid];
    float r = 1.f / (1.f + expf(-(o_r + w.bih[tid] + w.bhh[tid])));
    float z = 1.f / (1.f + expf(-(o_z + w.bih[128 + tid] + w.bhh[128 + tid])));
    float nn = tanhf(o_n + w.bih[256 + tid] + r * (o_g + w.bhh[256 + tid]));
    uu_reg = (1.f - z) * nn + z * sl[S_ZS + 128 + tid];
    sl[S_UU + tid] = uu_reg;
    float2 r2 = waveRed2(uu_reg, uu_reg * uu_reg);
    if ((tid & 63) == 0) { red[4 + (tid >> 6) * 2] = r2.x; red[5 + (tid >> 6) * 2] = r2.y; }
  }
  __syncthreads();  // B4
  if (tid < 128) {
    float sum = red[4] + red[6], sq = red[5] + red[7];
    float m = sum * (1.f / 128.f);
    float var = sq * (1.f / 128.f) - m * m;
    float rsq = rsqrtf(var + 1e-5f);
    sl[S_H2 + tid] = (uu_reg - m) * rsq * w.gmu[tid] + w.bmu[tid];
  }
  __syncthreads();  // B5
  // MLP up: 512 outputs, 2-way K-split, octo-packed
  {
    int q = tid & 511, kg = tid >> 9;
    const uint4* wc1 = (const uint4*)w.m1P + (size_t)(kg * 8) * 512 + q;
    const float* h = sl + S_H2 + kg * 64;
    float a0 = 0.f, a1 = 0.f, a2 = 0.f, a3 = 0.f;
    #pragma unroll
    for (int r = 0; r < 8; ++r)
      oct_fma(wc1[r * 512], h + 8 * r, a0, a1, a2, a3);
    sl[S_P1 + kg * 512 + q] = (a0 + a1) + (a2 + a3);
  }
  __syncthreads();  // B6
  if (tid < 512)
    sl[S_A1S + tid] = fmaxf(sl[S_P1 + tid] + sl[S_P1 + 512 + tid] + w.mb1[tid], 0.f);
  __syncthreads();  // B7
  // MLP down: 128 outputs, 8-way K-split, octo-packed
  {
    int d = tid & 127, qg = tid >> 7;
    const uint4* wc2 = (const uint4*)w.m2P + (size_t)(qg * 8) * 128 + d;
    const float* a = sl + S_A1S + qg * 64;
    float b0 = 0.f, b1 = 0.f, b2 = 0.f, b3 = 0.f;
    #pragma unroll
    for (int r = 0; r < 8; ++r)
      oct_fma(wc2[r * 128], a + 8 * r, b0, b1, b2, b3);
    sl[S_P1 + qg * 128 + d] = (b0 + b1) + (b2 + b3);
  }
  __syncthreads();  // B8
  if (tid < 128) {
    float o = w.mb2[tid];
    #pragma unroll
    for (int g = 0; g < 8; ++g) o += sl[S_P1 + g * 128 + tid];
    float uf = sl[S_UU + tid] + o;
    float xsv = sl[S_ZS + tid];
    float arg = sl[S_S2 + tid] - 2.f * uf * xsv + uf * uf + EPS_;
    float lsv = 0.5f * logf(fmaxf(arg, 1e-30f));
    sl[S_SNEW + tid] = uf;
    sl[S_SNEW + 128 + tid] = lsv;
  }
  __syncthreads();  // B9
  if (FINAL) return;
  float xv = 0.f;
  if (tid < 256) {
    xv = sl[S_SNEW + tid];
    float2 r2 = waveRed2(xv, xv * xv);
    if ((tid & 63) == 0) { red[8 + (tid >> 6) * 2] = r2.x; red[9 + (tid >> 6) * 2] = r2.y; }
  }
  __syncthreads();  // B10
  if (tid < 256) {
    float sum = red[8] + red[10] + red[12] + red[14];
    float sq = red[9] + red[11] + red[13] + red[15];
    float m2 = sum * (1.f / 256.f);
    float var2 = sq * (1.f / 256.f) - m2 * m2;
    float rs2 = rsqrtf(var2 + 1e-5f);
    float slv = (xv - m2) * rs2 * w.gsl[tid] + w.bsl[tid];
    sl[S_A1S + tid] = slv;
    if (tid < 128) mu[(size_t)(b * NS_ + i) * 128 + tid] = slv;
  }
  __syncthreads();  // B11
  slotTail1024(sl, b, i, tid, w.wqP, wcoef, cbuf);
}

// ---------- kvK: LN + MFMA k/v GEMM->bf16 (0..255) + slot prep (256..319) + packing (320..383) ----------
__global__ __launch_bounds__(1024, 1) void kvK(const float* __restrict__ inp,
    const float* __restrict__ gin, const float* __restrict__ bin,
    const float* __restrict__ slots_in, SW w, RW rw,
    unsigned* __restrict__ kb, unsigned* __restrict__ vb,
    float* __restrict__ mu, float* wcoef, float* cbuf, float* __restrict__ ws) {
  __shared__ __align__(16) float shm[9600];
  int tid = threadIdx.x;
  int blk = blockIdx.x;
  if (blk < 256) {
    float* xs = shm;            // [64][132]
    float* red = shm + 8448;    // [64][16]
    float* mrow = shm + 9472;
    float* rrow = shm + 9536;
    int rowbase = blk * 64;
    #pragma unroll
    for (int it = 0; it < 2; ++it) {
      int f = tid + it * 1024;
      int row = f >> 5, c4 = (f & 31) * 4;
      const float4 v = *(const float4*)&inp[(size_t)(rowbase + row) * 128 + c4];
      *(float4*)&xs[row * 132 + c4] = v;
    }
    __syncthreads();
    int row = tid >> 4, prt = tid & 15;
    float s = 0.f, s2 = 0.f;
    #pragma unroll
    for (int e = 0; e < 8; ++e) {
      float v = xs[row * 132 + prt * 8 + e];
      s += v; s2 = fmaf(v, v, s2);
    }
    red[row * 16 + prt] = s;
    __syncthreads();
    if (prt == 0) {
      float m = 0.f;
      #pragma unroll
      for (int q = 0; q < 16; ++q) m += red[row * 16 + q];
      mrow[row] = m * (1.f / 128.f);
    }
    __syncthreads();
    float m = mrow[row];
    red[row * 16 + prt] = s2;
    __syncthreads();
    if (prt == 0) {
      float v = 0.f;
      #pragma unroll
      for (int q = 0; q < 16; ++q) v += red[row * 16 + q];
      float var = v * (1.f / 128.f) - m * m;
      rrow[row] = rsqrtf(var + 1e-5f);
    }
    __syncthreads();
    float rs = rrow[row];
    #pragma unroll
    for (int e = 0; e < 8; ++e) {
      int c = prt * 8 + e;
      xs[row * 132 + c] = (xs[row * 132 + c] - m) * rs * gin[c] + bin[c];
    }
    __syncthreads();
    // MFMA GEMM: C[64x256] = xs_bf16[64x128] @ W[128x256]
    // wave wv: M-tile mt = wv>>2 (16 rows), N-tiles ng*4..ng*4+3 (64 cols)
    // B-fragments built inline from raw Wk/Wv (L2-hot; replaces tK launch)
    int l = tid & 63;
    int wv = __builtin_amdgcn_readfirstlane(threadIdx.x >> 6);
    int mt = wv >> 2, ng = wv & 3;
    const float* wmat = (ng < 2) ? rw.Wk : rw.Wv;
    int nloc0 = (ng & 1) * 64 + (l & 15);      // + t*16
    f32x4 acc0 = {0.f, 0.f, 0.f, 0.f};
    f32x4 acc1 = acc0, acc2 = acc0, acc3 = acc0;
    int mrow2 = mt * 16 + (l & 15);
    int kgrp = (l >> 4) << 3;
    #pragma unroll
    for (int ks = 0; ks < 4; ++ks) {
      int k0 = ks * 32 + kgrp;
      float4 xa = *(const float4*)&xs[mrow2 * 132 + k0];
      float4 xb = *(const float4*)&xs[mrow2 * 132 + k0 + 4];
      U8 ua;
      ua.q = make_uint4(packbf(xa.x, xa.y), packbf(xa.z, xa.w),
                        packbf(xb.x, xb.y), packbf(xb.z, xb.w));
      U8 bt[4];
      #pragma unroll
      for (int t = 0; t < 4; ++t) {
        const float* srcp = &wmat[(size_t)(nloc0 + t * 16) * 128 + k0];
        float4 wa = *(const float4*)srcp;
        float4 wb = *(const float4*)(srcp + 4);
        bt[t].q = make_uint4(packbf(wa.x, wa.y), packbf(wa.z, wa.w),
                             packbf(wb.x, wb.y), packbf(wb.z, wb.w));
      }
      acc0 = __builtin_amdgcn_mfma_f32_16x16x32_bf16(ua.v, bt[0].v, acc0, 0, 0, 0);
      acc1 = __builtin_amdgcn_mfma_f32_16x16x32_bf16(ua.v, bt[1].v, acc1, 0, 0, 0);
      acc2 = __builtin_amdgcn_mfma_f32_16x16x32_bf16(ua.v, bt[2].v, acc2, 0, 0, 0);
      acc3 = __builtin_amdgcn_mfma_f32_16x16x32_bf16(ua.v, bt[3].v, acc3, 0, 0, 0);
    }
    // store: D[m][n]: m = mt*16+(l>>4)*4+reg, n = (ng*4+t)*16+(l&15); pack pairs via shfl
    unsigned* outp = (ng < 2) ? kb : vb;
    int nbase = (ng & 1) * 64;
    #define STORE_TILE(ACC, T)                                                   \
      {                                                                          \
        _Pragma("unroll")                                                        \
        for (int reg = 0; reg < 4; ++reg) {                                      \
          float v = ACC[reg];                                                    \
          float vh = __shfl_xor(v, 1, 64);                                       \
          if (!(l & 1)) {                                                        \
            int mm = rowbase + mt * 16 + ((l >> 4) << 2) + reg;                  \
            int cp = (nbase + (T) * 16 + (l & 15)) >> 1;                         \
            outp[(size_t)mm * 64 + cp] = packbf(v, vh);                          \
          }                                                                      \
        }                                                                        \
      }
    STORE_TILE(acc0, 0)
    STORE_TILE(acc1, 1)
    STORE_TILE(acc2, 2)
    STORE_TILE(acc3, 3)
    #undef STORE_TILE
  } else if (blk < 320) {
    float* sl = shm;
    float* red = sl + S_RED;
    int sb = blk - 256;
    int b2 = sb >> 4, i = sb & 15;
    float xv = 0.f;
    if (tid < 256) {
      xv = slots_in[(size_t)(b2 * NS_ + i) * 256 + tid];
      float2 r2 = waveRed2(xv, xv * xv);
      if ((tid & 63) == 0) { red[8 + (tid >> 6) * 2] = r2.x; red[9 + (tid >> 6) * 2] = r2.y; }
    }
    __syncthreads();
    if (tid < 256) {
      float sum = red[8] + red[10] + red[12] + red[14];
      float sq = red[9] + red[11] + red[13] + red[15];
      float m = sum * (1.f / 256.f);
      float var = sq * (1.f / 256.f) - m * m;
      float rs = rsqrtf(var + 1e-5f);
      float slv = (xv - m) * rs * w.gsl[tid] + w.bsl[tid];
      sl[S_A1S + tid] = slv;
      if (tid < 128) mu[(size_t)(b2 * NS_ + i) * 128 + tid] = slv;
    }
    __syncthreads();
    slotTailF(sl, b2, i, tid, rw.Wq, wcoef, cbuf);
  } else {
    // packer blocks: octo-packed bf16 weights (consumed by rK/oK, which launch later)
    int gid = (blk - 320) * 1024 + tid;  // 0..65535
    uint4* wcP = (uint4*)(ws + OFF_WCP);
    uint4* m1P = (uint4*)(ws + OFF_M1P);
    uint4* m2P = (uint4*)(ws + OFF_M2P);
    uint4* wqP = (uint4*)(ws + OFF_WQP);
    uint4* o1P = (uint4*)(ws + OFF_O1P);
    uint4* o2P = (uint4*)(ws + OFF_O2P);
    if (gid < 32768) {  // o1P: [32 k-octs][1024 q]
      int ko = gid >> 10, q = gid & 1023;
      const float* src = &rw.oW1[q * 256 + 8 * ko];
      o1P[gid] = make_uint4(packbf(src[0], src[1]), packbf(src[2], src[3]),
                            packbf(src[4], src[5]), packbf(src[6], src[7]));
    }
    if (gid < 16384) {  // o2P: [128 k-octs][128 d]
      int ko = gid >> 7, d = gid & 127;
      const float* src = &rw.oW2[d * 1024 + 8 * ko];
      o2P[gid] = make_uint4(packbf(src[0], src[1]), packbf(src[2], src[3]),
                            packbf(src[4], src[5]), packbf(src[6], src[7]));
    }
    if (gid < 16384) {  // wcP: [32 k-octs][512 q] of virtual WC[256][512]
      int ko = gid >> 9, q = gid & 511;
      float v[8];
      #pragma unroll
      for (int j = 0; j < 8; ++j) {
        int dd = 8 * ko + j;
        float val;
        if (dd < 128) {
          val = (q < 384) ? rw.Wih[q * 128 + dd] : 0.f;
        } else {
          int dh = dd - 128;
          if (q < 256)      val = rw.Whh[q * 128 + dh];
          else if (q < 384) val = 0.f;
          else              val = rw.Whh[(q - 128) * 128 + dh];
        }
        v[j] = val;
      }
      wcP[gid] = make_uint4(packbf(v[0], v[1]), packbf(v[2], v[3]),
                            packbf(v[4], v[5]), packbf(v[6], v[7]));
    }
    if (gid < 8192) {  // m1P: [16 k-octs][512 q]
      int ko = gid >> 9, q = gid & 511;
      const float* src = &rw.mW1[q * 128 + 8 * ko];
      m1P[gid] = make_uint4(packbf(src[0], src[1]), packbf(src[2], src[3]),
                            packbf(src[4], src[5]), packbf(src[6], src[7]));
    }
    if (gid < 8192) {  // m2P: [64 k-octs][128 d]
      int ko = gid >> 7, d = gid & 127;
      const float* src = &rw.mW2[d * 512 + 8 * ko];
      m2P[gid] = make_uint4(packbf(src[0], src[1]), packbf(src[2], src[3]),
                            packbf(src[4], src[5]), packbf(src[6], src[7]));
    }
    if (gid < 2048) {  // wqP: [16 k-octs][128 o]
      int ko = gid >> 7, o = gid & 127;
      const float* src = &rw.Wq[o * 128 + 8 * ko];
      wqP[gid] = make_uint4(packbf(src[0], src[1]), packbf(src[2], src[3]),
                            packbf(src[4], src[5]), packbf(src[6], src[7]));
    }
  }
}

// ---------- pK: token pass per step (1024 threads, bf16 K/V in LDS) ----------
__global__ __launch_bounds__(1024, 1) void pK(const unsigned* __restrict__ kb,
    const unsigned* __restrict__ vb, const float* __restrict__ wcoef,
    const float* __restrict__ cbuf, float* __restrict__ part,
    float* __restrict__ attnu, int last) {
  __shared__ __align__(16) unsigned buf[64 * 68];   // K then V: [j][64 d-pair uints, pad 68]
  __shared__ __align__(16) float a1s[16 * 68];
  __shared__ float esum[16 * 64];
  int tid = threadIdx.x;
  int jt = blockIdx.x, b = blockIdx.y;
  size_t jrow = (size_t)(b * N_ + jt * 64);
  {
    int row = tid >> 4, oct = tid & 15;
    uint4 kv = *(const uint4*)&kb[(jrow + row) * 64 + oct * 4];
    *(uint4*)&buf[row * 68 + oct * 4] = kv;
  }
  __syncthreads();
  uint4 vr;
  {
    int row = tid >> 4, oct = tid & 15;
    vr = *(const uint4*)&vb[(jrow + row) * 64 + oct * 4];
  }
  // phase A: wave w owns slot w; lanes = tokens
  {
    int l = tid & 63;
    int w = __builtin_amdgcn_readfirstlane(threadIdx.x >> 6);
    const float4* wq4 = (const float4*)&wcoef[((size_t)b * 16 + w) * 256];
    float c0 = cbuf[b * NS_ + w];
    const uint4* kr = (const uint4*)&buf[l * 68];
    float a0 = 0.f, a1 = 0.f, a2 = 0.f, a3 = 0.f;
    #pragma unroll 8
    for (int i = 0; i < 16; ++i) {
      uint4 kv = kr[i];
      float4 wA = wq4[4 * i], wB = wq4[4 * i + 1], wC = wq4[4 * i + 2], wD = wq4[4 * i + 3];
      float k0 = bf_lo(kv.x), k1 = bf_hi(kv.x);
      float k2 = bf_lo(kv.y), k3 = bf_hi(kv.y);
      float k4 = bf_lo(kv.z), k5 = bf_hi(kv.z);
      float k6 = bf_lo(kv.w), k7 = bf_hi(kv.w);
      a0 = fmaf(fmaf(wA.y, k0, wA.x), k0, a0);
      a1 = fmaf(fmaf(wA.w, k1, wA.z), k1, a1);
      a2 = fmaf(fmaf(wB.y, k2, wB.x), k2, a2);
      a3 = fmaf(fmaf(wB.w, k3, wB.z), k3, a3);
      a0 = fmaf(fmaf(wC.y, k4, wC.x), k4, a0);
      a1 = fmaf(fmaf(wC.w, k5, wC.z), k5, a1);
      a2 = fmaf(fmaf(wD.y, k6, wD.x), k6, a2);
      a3 = fmaf(fmaf(wD.w, k7, wD.z), k7, a3);
    }
    float e0 = expf(-(c0 + (a0 + a1) + (a2 + a3))) + EPS_;
    esum[w * 64 + l] = e0;
    __syncthreads();
    float tot = 0.f;
    #pragma unroll
    for (int q = 0; q < 16; ++q) tot += esum[q * 64 + l];
    float av = e0 / tot;
    a1s[w * 68 + l] = av;
    if (last) attnu[(size_t)(b * NS_ + w) * N_ + jt * 64 + l] = av;
  }
  __syncthreads();
  {
    int row = tid >> 4, oct = tid & 15;
    *(uint4*)&buf[row * 68 + oct * 4] = vr;
  }
  __syncthreads();
  // phase B: wave ii owns slot ii; lane (l&31) owns d-quad; j split across lane halves
  {
    int ii = __builtin_amdgcn_readfirstlane(threadIdx.x >> 6);
    int lh = (tid >> 5) & 1;
    int dp = tid & 31;
    float av0 = 0, av1 = 0, av2 = 0, av3 = 0, aw0 = 0, aw1 = 0, aw2 = 0, aw3 = 0, rsum = 0;
    #pragma unroll
    for (int jj = 0; jj < 32; jj += 4) {
      int j = lh * 32 + jj;
      float4 a4 = *(const float4*)&a1s[ii * 68 + j];
      float aarr[4] = {a4.x, a4.y, a4.z, a4.w};
      #pragma unroll
      for (int e = 0; e < 4; ++e) {
        float a = aarr[e];
        uint2 q = *(const uint2*)&buf[(j + e) * 68 + dp * 2];
        float v0 = bf_lo(q.x), v1 = bf_hi(q.x), v2 = bf_lo(q.y), v3 = bf_hi(q.y);
        rsum += a;
        float m0 = a * v0, m1 = a * v1, m2 = a * v2, m3 = a * v3;
        av0 += m0; av1 += m1; av2 += m2; av3 += m3;
        aw0 = fmaf(m0, v0, aw0); aw1 = fmaf(m1, v1, aw1);
        aw2 = fmaf(m2, v2, aw2); aw3 = fmaf(m3, v3, aw3);
      }
    }
    av0 += __shfl_down(av0, 32, 64); av1 += __shfl_down(av1, 32, 64);
    av2 += __shfl_down(av2, 32, 64); av3 += __shfl_down(av3, 32, 64);
    aw0 += __shfl_down(aw0, 32, 64); aw1 += __shfl_down(aw1, 32, 64);
    aw2 += __shfl_down(aw2, 32, 64); aw3 += __shfl_down(aw3, 32, 64);
    rsum += __shfl_down(rsum, 32, 64);
    if ((tid & 63) < 32) {
      float* pr = &part[((size_t)(b * NT_ + jt) * NS_ + ii) * 260];
      *(float4*)&pr[dp * 4] = make_float4(av0, av1, av2, av3);
      *(float4*)&pr[128 + dp * 4] = make_float4(aw0, aw1, aw2, aw3);
      if ((tid & 63) == 0) pr[256] = rsum;
    }
  }
}

// ---------- rK: per-slot update (steps 0..2), 64 blocks x 1024 ----------
__global__ __launch_bounds__(1024, 1) void rK(const float* __restrict__ part,
    float* mu, float* wcoef, float* cbuf, SW w) {
  __shared__ __align__(16) float sl[S_TOT];
  int tid = threadIdx.x;
  int b = blockIdx.x >> 4, i = blockIdx.x & 15;
  slotUpdateT<0>(sl, b, i, tid, part, mu, wcoef, cbuf, w);
}

// ---------- oK: final slot update + out MLP (0..63) + attn normalize (64..127) ----------
__global__ __launch_bounds__(1024, 1) void oK(const float* __restrict__ part,
    float* mu, SW w,
    const unsigned* __restrict__ o1P, const float* __restrict__ ob1,
    const unsigned* __restrict__ o2P, const float* __restrict__ ob2,
    const float* __restrict__ attnu, float* __restrict__ out) {
  __shared__ __align__(16) float sl[S_TOT];
  int blk = blockIdx.x, tid = threadIdx.x;
  const size_t pstr = (size_t)NS_ * 260;
  if (blk >= 64) {
    int r = blk - 64;
    int b = r >> 4, i = r & 15;
    size_t pbase = ((size_t)(b * NT_) * NS_ + i) * 260;
    if (tid < 64) {
      float v = waveRed1(part[pbase + (size_t)tid * pstr + 256]);
      if (tid == 0) sl[0] = v;
    }
    __syncthreads();
    float rs = sl[0];
    int base = r * 4096 + tid * 4;
    float4 v = *(const float4*)&attnu[base];
    v.x /= rs; v.y /= rs; v.z /= rs; v.w /= rs;
    *(float4*)&out[8192 + base] = v;
    return;
  }
  int b = blk >> 4, i = blk & 15;
  slotUpdateT<1>(sl, b, i, tid, part, mu, (float*)nullptr, (float*)nullptr, w);
  // out-MLP up: 1024 outputs, 1/thread, octo-packed; h1 -> S_P1
  {
    const float* sn = sl + S_SNEW;
    const uint4* o1 = (const uint4*)o1P;
    float a0 = 0.f, a1 = 0.f, a2 = 0.f, a3 = 0.f;
    #pragma unroll 8
    for (int r = 0; r < 16; ++r) {
      oct_fma(o1[r * 1024 + tid], sn + 8 * r, a0, a1, a2, a3);
      oct_fma(o1[(16 + r) * 1024 + tid], sn + 128 + 8 * r, a0, a1, a2, a3);
    }
    sl[S_P1 + tid] = fmaxf((a0 + a1) + (a2 + a3) + ob1[tid], 0.f);
  }
  __syncthreads();
  // out-MLP down: 128 outputs, 8-way K-split, octo-packed
  float dpart = 0.f;
  {
    int d = tid & 127, qg = tid >> 7;
    const uint4* wc2 = (const uint4*)o2P + (size_t)(qg * 16) * 128 + d;
    const float* h = sl + S_P1 + qg * 128;
    float b0 = 0.f, b1 = 0.f, b2 = 0.f, b3 = 0.f;
    #pragma unroll 8
    for (int r = 0; r < 16; ++r)
      oct_fma(wc2[r * 128], h + 8 * r, b0, b1, b2, b3);
    dpart = (b0 + b1) + (b2 + b3);
  }
  __syncthreads();
  {
    int d = tid & 127, qg = tid >> 7;
    sl[qg * 128 + d] = dpart;
  }
  __syncthreads();
  if (tid < 128) {
    float o = ob2[tid];
    #pragma unroll
    for (int g = 0; g < 8; ++g) o += sl[g * 128 + tid];
    out[(size_t)blk * 128 + tid] = o;
  }
}

extern "C" void kernel_launch(void* const* d_in, const int* in_sizes, int n_in,
                              void* d_out, int out_size, void* d_ws, size_t ws_size,
                              hipStream_t stream) {
  const float* slots_in = (const float*)d_in[0];
  const float* inputs   = (const float*)d_in[1];
  const float* Wq  = (const float*)d_in[2];
  const float* Wk  = (const float*)d_in[3];
  const float* Wv  = (const float*)d_in[4];
  const float* Wih = (const float*)d_in[5];
  const float* Whh = (const float*)d_in[6];
  const float* bih = (const float*)d_in[7];
  const float* bhh = (const float*)d_in[8];
  const float* mW1 = (const float*)d_in[9];
  const float* mb1 = (const float*)d_in[10];
  const float* mW2 = (const float*)d_in[11];
  const float* mb2 = (const float*)d_in[12];
  const float* g_in  = (const float*)d_in[13];
  const float* be_in = (const float*)d_in[14];
  const float* g_sl  = (const float*)d_in[15];
  const float* be_sl = (const float*)d_in[16];
  const float* g_mu  = (const float*)d_in[17];
  const float* be_mu = (const float*)d_in[18];
  const float* oW1 = (const float*)d_in[19];
  const float* ob1 = (const float*)d_in[20];
  const float* oW2 = (const float*)d_in[21];
  const float* ob2 = (const float*)d_in[22];
  float* ws  = (float*)d_ws;
  float* out = (float*)d_out;
  (void)in_sizes; (void)n_in; (void)out_size; (void)ws_size;

  SW w;
  w.wcP = (const unsigned*)(ws + OFF_WCP);
  w.m1P = (const unsigned*)(ws + OFF_M1P);
  w.m2P = (const unsigned*)(ws + OFF_M2P);
  w.wqP = (const unsigned*)(ws + OFF_WQP);
  w.bih = bih; w.bhh = bhh; w.mb1 = mb1; w.mb2 = mb2;
  w.gmu = g_mu; w.bmu = be_mu; w.gsl = g_sl; w.bsl = be_sl;
  RW rw;
  rw.Wq = Wq; rw.Wk = Wk; rw.Wv = Wv; rw.Wih = Wih; rw.Whh = Whh;
  rw.mW1 = mW1; rw.mW2 = mW2; rw.oW1 = oW1; rw.oW2 = oW2;

  hipLaunchKernelGGL(kvK, dim3(384), dim3(1024), 0, stream,
                     inputs, g_in, be_in, slots_in, w, rw,
                     (unsigned*)(ws + OFF_K), (unsigned*)(ws + OFF_V),
                     ws + OFF_MU, ws + OFF_WCOEF, ws + OFF_C, ws);
  for (int s = 0; s < 4; ++s) {
    hipLaunchKernelGGL(pK, dim3(64, 4), dim3(1024), 0, stream,
                       (const unsigned*)(ws + OFF_K), (const unsigned*)(ws + OFF_V),
                       ws + OFF_WCOEF, ws + OFF_C,
                       ws + OFF_PART, ws + OFF_ATTNU, (s == 3) ? 1 : 0);
    if (s < 3) {
      hipLaunchKernelGGL(rK, dim3(64), dim3(1024), 0, stream,
                         ws + OFF_PART, ws + OFF_MU, ws + OFF_WCOEF, ws + OFF_C, w);
    }
  }
  hipLaunchKernelGGL(oK, dim3(128), dim3(1024), 0, stream,
                     ws + OFF_PART, ws + OFF_MU, w,
                     (const unsigned*)(ws + OFF_O1P), ob1,
                     (const unsigned*)(ws + OFF_O2P), ob2, ws + OFF_ATTNU, out);
}

// Round 18
// 126.181 us; speedup vs baseline: 1.0497x; 1.0497x over previous
//
#include <hip/hip_runtime.h>
#include <math.h>

#define B_ 4
#define N_ 4096
#define D_ 128
#define NS_ 16
#define NT_ 64
#define SCALE_ 0.08838834764831843f
#define EPS_ 1e-10f

typedef __attribute__((ext_vector_type(8))) short bf16x8;
typedef __attribute__((ext_vector_type(4))) float f32x4;
union U8 { uint4 q; bf16x8 v; };

// workspace offsets (in 4-byte words)
#define OFF_K      ((size_t)0)                    /* bf16 [B*N][128] = B*N*64 words */
#define OFF_V      (OFF_K + (size_t)B_*N_*64)
#define OFF_WCP    (OFF_V + (size_t)B_*N_*64)     /* uint4 [32][512] octo-packed GRU */
#define OFF_M1P    (OFF_WCP + 64*512*2)           /* uint4 [16][512] */
#define OFF_M2P    (OFF_M1P + 32*512*2)           /* uint4 [64][128] */
#define OFF_WQP    (OFF_M2P + 128*128*2)          /* uint4 [16][128] */
#define OFF_O1P    (OFF_WQP + 32*128*2)           /* uint4 [32][1024] */
#define OFF_O2P    (OFF_O1P + (size_t)64*1024*2)  /* uint4 [128][128] */
#define OFF_WTF    (OFF_O2P + 256*128*2)          /* uint4 [4][16][64] B-fragments */
#define OFF_MU     (OFF_WTF + 16384)
#define OFF_WCOEF  (OFF_MU + (size_t)B_*NS_*128)  /* [b][16][128][2] */
#define OFF_C      (OFF_WCOEF + (size_t)B_*128*32)
#define OFF_PART   (OFF_C + 64)
#define OFF_ATTNU  (OFF_PART + (size_t)B_*NT_*NS_*260)

// slot scratch offsets (floats)
#define S_ZS    0
#define S_S2    256
#define S_UU    384
#define S_H2    512
#define S_A1S   640
#define S_SNEW  1152
#define S_QM    1408
#define S_QL    1536
#define S_RED   1664
#define S_P1    2688
#define S_TOT   3712

__device__ __forceinline__ float bf_lo(unsigned p) { return __uint_as_float(p << 16); }
__device__ __forceinline__ float bf_hi(unsigned p) { return __uint_as_float(p & 0xffff0000u); }
__device__ __forceinline__ unsigned packbf(float lo, float hi) {
  unsigned ul = __float_as_uint(lo), uh = __float_as_uint(hi);
  ul = (ul + 0x7fffu + ((ul >> 16) & 1u)) >> 16;
  uh = (uh + 0x7fffu + ((uh >> 16) & 1u)) >> 16;
  return (ul & 0xffffu) | (uh << 16);
}

__device__ __forceinline__ float waveRed1(float a) {
  #pragma unroll
  for (int off = 32; off > 0; off >>= 1) a += __shfl_down(a, off, 64);
  return a;
}
__device__ __forceinline__ float2 waveRed2(float a, float b) {
  #pragma unroll
  for (int off = 32; off > 0; off >>= 1) {
    a += __shfl_down(a, off, 64);
    b += __shfl_down(b, off, 64);
  }
  return make_float2(a, b);
}

// octo-FMA helper: 8 bf16 weights (uint4) x 8 activations
__device__ __forceinline__ void oct_fma(const uint4& p, const float* s,
    float& a0, float& a1, float& a2, float& a3) {
  a0 = fmaf(s[0], bf_lo(p.x), a0);
  a1 = fmaf(s[1], bf_hi(p.x), a1);
  a2 = fmaf(s[2], bf_lo(p.y), a2);
  a3 = fmaf(s[3], bf_hi(p.y), a3);
  a0 = fmaf(s[4], bf_lo(p.z), a0);
  a1 = fmaf(s[5], bf_hi(p.z), a1);
  a2 = fmaf(s[6], bf_lo(p.w), a2);
  a3 = fmaf(s[7], bf_hi(p.w), a3);
}

// packed-weight + bias bundle
struct SW {
  const unsigned* wcP;
  const unsigned* m1P;
  const unsigned* m2P;
  const unsigned* wqP;
  const float* bih; const float* bhh;
  const float* mb1; const float* mb2;
  const float* gmu; const float* bmu;
  const float* gsl; const float* bsl;
};
// raw f32 weights (packers + kvK slot-prep)
struct RW {
  const float* Wq;
  const float* Wih; const float* Whh;
  const float* mW1; const float* mW2;
  const float* oW1; const float* oW2;
};

// shared merge for slot tails: qpart in S_P1[4][256] -> wcoef/cbuf
__device__ __forceinline__ void tailMerge(float* sl, int b, int i, int tid,
    float* wcoef, float* cbuf) {
  float* red = sl + S_RED;
  if (tid < 256) {
    float q = sl[S_P1 + tid] + sl[S_P1 + 256 + tid] + sl[S_P1 + 512 + tid] + sl[S_P1 + 768 + tid];
    if (tid < 128) sl[S_QM + tid] = q; else sl[S_QL + (tid - 128)] = q;
  }
  __syncthreads();
  if (tid < 128) {
    float iv = expf(-2.f * sl[S_QL + tid]);
    float a1 = SCALE_ * iv;
    float a2 = -2.f * SCALE_ * iv * sl[S_QM + tid];
    float* wrow = &wcoef[(((size_t)b * 16 + i) * 128 + tid) * 2];
    wrow[0] = a2;
    wrow[1] = a1;
    float cp = SCALE_ * iv * sl[S_QM + tid] * sl[S_QM + tid];
    float r = waveRed1(cp);
    if ((tid & 63) == 0) red[16 + (tid >> 6)] = r;
  }
  __syncthreads();
  if (tid == 0) cbuf[b * NS_ + i] = red[16] + red[17];
}

// packed-wq tail (rK): sl[S_A1S..+255] = LN'd slot row
__device__ __forceinline__ void slotTail1024(float* sl, int b, int i, int tid,
    const unsigned* __restrict__ wqPu, float* wcoef, float* cbuf) {
  {
    int rest = tid & 255, kg = tid >> 8;
    int wh = rest >> 7, o = rest & 127;
    const uint4* wq = (const uint4*)wqPu + (size_t)(kg * 4) * 128 + o;
    const float* s = sl + S_A1S + wh * 128 + kg * 32;
    float a0 = 0.f, a1 = 0.f, a2 = 0.f, a3 = 0.f;
    #pragma unroll
    for (int r = 0; r < 4; ++r)
      oct_fma(wq[r * 128], s + 8 * r, a0, a1, a2, a3);
    sl[S_P1 + kg * 256 + rest] = (a0 + a1) + (a2 + a3);
  }
  __syncthreads();
  tailMerge(sl, b, i, tid, wcoef, cbuf);
}

// f32 raw-Wq tail (kvK slot-prep only; wqP not yet written in this launch)
__device__ __forceinline__ void slotTailF(float* sl, int b, int i, int tid,
    const float* __restrict__ Wq, float* wcoef, float* cbuf) {
  {
    int rest = tid & 255, kg = tid >> 8;
    int wh = rest >> 7, o = rest & 127;
    const float4* wr = (const float4*)&Wq[(size_t)o * 128 + kg * 32];
    const float* s = sl + S_A1S + wh * 128 + kg * 32;
    float a0 = 0.f, a1 = 0.f, a2 = 0.f, a3 = 0.f;
    #pragma unroll
    for (int r = 0; r < 8; ++r) {
      float4 wv = wr[r];
      a0 = fmaf(s[4 * r],     wv.x, a0);
      a1 = fmaf(s[4 * r + 1], wv.y, a1);
      a2 = fmaf(s[4 * r + 2], wv.z, a2);
      a3 = fmaf(s[4 * r + 3], wv.w, a3);
    }
    sl[S_P1 + kg * 256 + rest] = (a0 + a1) + (a2 + a3);
  }
  __syncthreads();
  tailMerge(sl, b, i, tid, wcoef, cbuf);
}

// 1024-thread slot update. FINAL=0: full incl. next-step prep. FINAL=1: stop with snew in LDS.
template <int FINAL>
__device__ void slotUpdateT(float* sl, int b, int i, int tid,
    const float* __restrict__ part, float* mu, float* wcoef, float* cbuf, SW w) {
  float* red = sl + S_RED;
  size_t pbase = ((size_t)(b * NT_) * NS_ + i) * 260;
  const size_t pstr = (size_t)NS_ * 260;
  {
    int g = tid >> 8, e = tid & 255;
    float s = 0.f;
    #pragma unroll 16
    for (int t = 0; t < 16; ++t) s += part[pbase + (size_t)(g * 16 + t) * pstr + e];
    sl[S_P1 + g * 256 + e] = s;
  }
  if (tid < 64) {
    float rtv = waveRed1(part[pbase + (size_t)tid * pstr + 256]);
    if (tid == 0) red[0] = rtv;
  }
  __syncthreads();  // B1
  float rt = red[0];
  if (tid < 256) {
    float s = sl[S_P1 + tid] + sl[S_P1 + 256 + tid] + sl[S_P1 + 512 + tid] + sl[S_P1 + 768 + tid];
    if (tid < 128) sl[S_ZS + tid] = s / rt; else sl[S_S2 + tid - 128] = s / rt;
  } else if (tid < 384) {
    sl[S_ZS + tid - 128] = mu[(size_t)(b * NS_ + i) * 128 + (tid - 256)];
  }
  __syncthreads();  // B2
  // GRU matvec: 512 outputs, 2-way K-split, octo-packed
  {
    int q = tid & 511, kg = tid >> 9;
    const uint4* wcol = (const uint4*)w.wcP + (size_t)(kg * 16) * 512 + q;
    const float* xz = sl + S_ZS + kg * 128;
    float a0 = 0.f, a1 = 0.f, a2 = 0.f, a3 = 0.f;
    #pragma unroll
    for (int r = 0; r < 16; ++r)
      oct_fma(wcol[r * 512], xz + 8 * r, a0, a1, a2, a3);
    sl[S_P1 + kg * 512 + q] = (a0 + a1) + (a2 + a3);
  }
  __syncthreads();  // B3
  float uu_reg = 0.f;
  if (tid < 128) {
    float o_r = sl[S_P1 + tid] + sl[S_P1 + 512 + tid];
    float o_z = sl[S_P1 + 128 + tid] + sl[S_P1 + 640 + tid];
    float o_n = sl[S_P1 + 256 + tid] + sl[S_P1 + 768 + tid];
    float o_g = sl[S_P1 + 384 + tid] + sl[S_P1 + 896 + tid];
    float r = 1.f / (1.f + expf(-(o_r + w.bih[tid] + w.bhh[tid])));
    float z = 1.f / (1.f + expf(-(o_z + w.bih[128 + tid] + w.bhh[128 + tid])));
    float nn = tanhf(o_n + w.bih[256 + tid] + r * (o_g + w.bhh[256 + tid]));
    uu_reg = (1.f - z) * nn + z * sl[S_ZS + 128 + tid];
    sl[S_UU + tid] = uu_reg;
    float2 r2 = waveRed2(uu_reg, uu_reg * uu_reg);
    if ((tid & 63) == 0) { red[4 + (tid >> 6) * 2] = r2.x; red[5 + (tid >> 6) * 2] = r2.y; }
  }
  __syncthreads();  // B4
  if (tid < 128) {
    float sum = red[4] + red[6], sq = red[5] + red[7];
    float m = sum * (1.f / 128.f);
    float var = sq * (1.f / 128.f) - m * m;
    float rsq = rsqrtf(var + 1e-5f);
    sl[S_H2 + tid] = (uu_reg - m) * rsq * w.gmu[tid] + w.bmu[tid];
  }
  __syncthreads();  // B5
  // MLP up: 512 outputs, 2-way K-split, octo-packed
  {
    int q = tid & 511, kg = tid >> 9;
    const uint4* wc1 = (const uint4*)w.m1P + (size_t)(kg * 8) * 512 + q;
    const float* h = sl + S_H2 + kg * 64;
    float a0 = 0.f, a1 = 0.f, a2 = 0.f, a3 = 0.f;
    #pragma unroll
    for (int r = 0; r < 8; ++r)
      oct_fma(wc1[r * 512], h + 8 * r, a0, a1, a2, a3);
    sl[S_P1 + kg * 512 + q] = (a0 + a1) + (a2 + a3);
  }
  __syncthreads();  // B6
  if (tid < 512)
    sl[S_A1S + tid] = fmaxf(sl[S_P1 + tid] + sl[S_P1 + 512 + tid] + w.mb1[tid], 0.f);
  __syncthreads();  // B7
  // MLP down: 128 outputs, 8-way K-split, octo-packed
  {
    int d = tid & 127, qg = tid >> 7;
    const uint4* wc2 = (const uint4*)w.m2P + (size_t)(qg * 8) * 128 + d;
    const float* a = sl + S_A1S + qg * 64;
    float b0 = 0.f, b1 = 0.f, b2 = 0.f, b3 = 0.f;
    #pragma unroll
    for (int r = 0; r < 8; ++r)
      oct_fma(wc2[r * 128], a + 8 * r, b0, b1, b2, b3);
    sl[S_P1 + qg * 128 + d] = (b0 + b1) + (b2 + b3);
  }
  __syncthreads();  // B8
  if (tid < 128) {
    float o = w.mb2[tid];
    #pragma unroll
    for (int g = 0; g < 8; ++g) o += sl[S_P1 + g * 128 + tid];
    float uf = sl[S_UU + tid] + o;
    float xsv = sl[S_ZS + tid];
    float arg = sl[S_S2 + tid] - 2.f * uf * xsv + uf * uf + EPS_;
    float lsv = 0.5f * logf(fmaxf(arg, 1e-30f));
    sl[S_SNEW + tid] = uf;
    sl[S_SNEW + 128 + tid] = lsv;
  }
  __syncthreads();  // B9
  if (FINAL) return;
  float xv = 0.f;
  if (tid < 256) {
    xv = sl[S_SNEW + tid];
    float2 r2 = waveRed2(xv, xv * xv);
    if ((tid & 63) == 0) { red[8 + (tid >> 6) * 2] = r2.x; red[9 + (tid >> 6) * 2] = r2.y; }
  }
  __syncthreads();  // B10
  if (tid < 256) {
    float sum = red[8] + red[10] + red[12] + red[14];
    float sq = red[9] + red[11] + red[13] + red[15];
    float m2 = sum * (1.f / 256.f);
    float var2 = sq * (1.f / 256.f) - m2 * m2;
    float rs2 = rsqrtf(var2 + 1e-5f);
    float slv = (xv - m2) * rs2 * w.gsl[tid] + w.bsl[tid];
    sl[S_A1S + tid] = slv;
    if (tid < 128) mu[(size_t)(b * NS_ + i) * 128 + tid] = slv;
  }
  __syncthreads();  // B11
  slotTail1024(sl, b, i, tid, w.wqP, wcoef, cbuf);
}

// ---------- tK: build MFMA B-fragments from raw Wk/Wv (bf16) ----------
// wtF[ks][nt][l]: 8 bf16 = W[n = nt*16+(l&15)][k = ks*32+(l>>4)*8 .. +7]
__global__ __launch_bounds__(256) void tK(const float* __restrict__ Wk,
    const float* __restrict__ Wv, uint4* __restrict__ wtF) {
  int fi = blockIdx.x * 256 + threadIdx.x;   // 4096 fragments
  int ks = fi >> 10, rem = fi & 1023;
  int nt = rem >> 6, l = rem & 63;
  int n = nt * 16 + (l & 15);
  int k0 = ks * 32 + ((l >> 4) << 3);
  const float* src = (n < 128) ? &Wk[(size_t)n * 128 + k0] : &Wv[(size_t)(n - 128) * 128 + k0];
  wtF[fi] = make_uint4(packbf(src[0], src[1]), packbf(src[2], src[3]),
                       packbf(src[4], src[5]), packbf(src[6], src[7]));
}

// ---------- kvK: LN + MFMA k/v GEMM->bf16 (0..255) + slot prep (256..319) + packing (320..383) ----------
__global__ __launch_bounds__(1024, 1) void kvK(const float* __restrict__ inp,
    const uint4* __restrict__ wtF,
    const float* __restrict__ gin, const float* __restrict__ bin,
    const float* __restrict__ slots_in, SW w, RW rw,
    unsigned* __restrict__ kb, unsigned* __restrict__ vb,
    float* __restrict__ mu, float* wcoef, float* cbuf, float* __restrict__ ws) {
  __shared__ __align__(16) float shm[9600];
  int tid = threadIdx.x;
  int blk = blockIdx.x;
  if (blk < 256) {
    float* xs = shm;            // [64][132]
    float* red = shm + 8448;    // [64][16]
    float* mrow = shm + 9472;
    float* rrow = shm + 9536;
    int rowbase = blk * 64;
    #pragma unroll
    for (int it = 0; it < 2; ++it) {
      int f = tid + it * 1024;
      int row = f >> 5, c4 = (f & 31) * 4;
      const float4 v = *(const float4*)&inp[(size_t)(rowbase + row) * 128 + c4];
      *(float4*)&xs[row * 132 + c4] = v;
    }
    __syncthreads();
    int row = tid >> 4, prt = tid & 15;
    float s = 0.f, s2 = 0.f;
    #pragma unroll
    for (int e = 0; e < 8; ++e) {
      float v = xs[row * 132 + prt * 8 + e];
      s += v; s2 = fmaf(v, v, s2);
    }
    red[row * 16 + prt] = s;
    __syncthreads();
    if (prt == 0) {
      float m = 0.f;
      #pragma unroll
      for (int q = 0; q < 16; ++q) m += red[row * 16 + q];
      mrow[row] = m * (1.f / 128.f);
    }
    __syncthreads();
    float m = mrow[row];
    red[row * 16 + prt] = s2;
    __syncthreads();
    if (prt == 0) {
      float v = 0.f;
      #pragma unroll
      for (int q = 0; q < 16; ++q) v += red[row * 16 + q];
      float var = v * (1.f / 128.f) - m * m;
      rrow[row] = rsqrtf(var + 1e-5f);
    }
    __syncthreads();
    float rs = rrow[row];
    #pragma unroll
    for (int e = 0; e < 8; ++e) {
      int c = prt * 8 + e;
      xs[row * 132 + c] = (xs[row * 132 + c] - m) * rs * gin[c] + bin[c];
    }
    __syncthreads();
    // MFMA GEMM: C[64x256] = xs_bf16[64x128] @ W[128x256]
    // wave wv: M-tile mt = wv>>2 (16 rows), N-tiles ng*4..ng*4+3 (64 cols)
    int l = tid & 63;
    int wv = __builtin_amdgcn_readfirstlane(threadIdx.x >> 6);
    int mt = wv >> 2, ng = wv & 3;
    f32x4 acc0 = {0.f, 0.f, 0.f, 0.f};
    f32x4 acc1 = acc0, acc2 = acc0, acc3 = acc0;
    int mrow2 = mt * 16 + (l & 15);
    int kgrp = (l >> 4) << 3;
    #pragma unroll
    for (int ks = 0; ks < 4; ++ks) {
      float4 xa = *(const float4*)&xs[mrow2 * 132 + ks * 32 + kgrp];
      float4 xb = *(const float4*)&xs[mrow2 * 132 + ks * 32 + kgrp + 4];
      U8 ua;
      ua.q = make_uint4(packbf(xa.x, xa.y), packbf(xa.z, xa.w),
                        packbf(xb.x, xb.y), packbf(xb.z, xb.w));
      U8 b0; b0.q = wtF[(ks * 16 + ng * 4 + 0) * 64 + l];
      U8 b1; b1.q = wtF[(ks * 16 + ng * 4 + 1) * 64 + l];
      U8 b2; b2.q = wtF[(ks * 16 + ng * 4 + 2) * 64 + l];
      U8 b3; b3.q = wtF[(ks * 16 + ng * 4 + 3) * 64 + l];
      acc0 = __builtin_amdgcn_mfma_f32_16x16x32_bf16(ua.v, b0.v, acc0, 0, 0, 0);
      acc1 = __builtin_amdgcn_mfma_f32_16x16x32_bf16(ua.v, b1.v, acc1, 0, 0, 0);
      acc2 = __builtin_amdgcn_mfma_f32_16x16x32_bf16(ua.v, b2.v, acc2, 0, 0, 0);
      acc3 = __builtin_amdgcn_mfma_f32_16x16x32_bf16(ua.v, b3.v, acc3, 0, 0, 0);
    }
    // store: D[m][n]: m = mt*16+(l>>4)*4+reg, n = (ng*4+t)*16+(l&15); pack pairs via shfl
    unsigned* outp = (ng < 2) ? kb : vb;
    int nbase = (ng & 1) * 64;  // column offset within the 128-col half
    #define STORE_TILE(ACC, T)                                                   \
      {                                                                          \
        _Pragma("unroll")                                                        \
        for (int reg = 0; reg < 4; ++reg) {                                      \
          float v = ACC[reg];                                                    \
          float vh = __shfl_xor(v, 1, 64);                                       \
          if (!(l & 1)) {                                                        \
            int mm = rowbase + mt * 16 + ((l >> 4) << 2) + reg;                  \
            int cp = (nbase + (T) * 16 + (l & 15)) >> 1;                         \
            outp[(size_t)mm * 64 + cp] = packbf(v, vh);                          \
          }                                                                      \
        }                                                                        \
      }
    STORE_TILE(acc0, 0)
    STORE_TILE(acc1, 1)
    STORE_TILE(acc2, 2)
    STORE_TILE(acc3, 3)
    #undef STORE_TILE
  } else if (blk < 320) {
    float* sl = shm;
    float* red = sl + S_RED;
    int sb = blk - 256;
    int b2 = sb >> 4, i = sb & 15;
    float xv = 0.f;
    if (tid < 256) {
      xv = slots_in[(size_t)(b2 * NS_ + i) * 256 + tid];
      float2 r2 = waveRed2(xv, xv * xv);
      if ((tid & 63) == 0) { red[8 + (tid >> 6) * 2] = r2.x; red[9 + (tid >> 6) * 2] = r2.y; }
    }
    __syncthreads();
    if (tid < 256) {
      float sum = red[8] + red[10] + red[12] + red[14];
      float sq = red[9] + red[11] + red[13] + red[15];
      float m = sum * (1.f / 256.f);
      float var = sq * (1.f / 256.f) - m * m;
      float rs = rsqrtf(var + 1e-5f);
      float slv = (xv - m) * rs * w.gsl[tid] + w.bsl[tid];
      sl[S_A1S + tid] = slv;
      if (tid < 128) mu[(size_t)(b2 * NS_ + i) * 128 + tid] = slv;
    }
    __syncthreads();
    slotTailF(sl, b2, i, tid, rw.Wq, wcoef, cbuf);
  } else {
    // packer blocks: octo-packed bf16 weights (consumed by rK/oK, which launch later)
    int gid = (blk - 320) * 1024 + tid;  // 0..65535
    uint4* wcP = (uint4*)(ws + OFF_WCP);
    uint4* m1P = (uint4*)(ws + OFF_M1P);
    uint4* m2P = (uint4*)(ws + OFF_M2P);
    uint4* wqP = (uint4*)(ws + OFF_WQP);
    uint4* o1P = (uint4*)(ws + OFF_O1P);
    uint4* o2P = (uint4*)(ws + OFF_O2P);
    if (gid < 32768) {  // o1P: [32 k-octs][1024 q]
      int ko = gid >> 10, q = gid & 1023;
      const float* src = &rw.oW1[q * 256 + 8 * ko];
      o1P[gid] = make_uint4(packbf(src[0], src[1]), packbf(src[2], src[3]),
                            packbf(src[4], src[5]), packbf(src[6], src[7]));
    }
    if (gid < 16384) {  // o2P: [128 k-octs][128 d]
      int ko = gid >> 7, d = gid & 127;
      const float* src = &rw.oW2[d * 1024 + 8 * ko];
      o2P[gid] = make_uint4(packbf(src[0], src[1]), packbf(src[2], src[3]),
                            packbf(src[4], src[5]), packbf(src[6], src[7]));
    }
    if (gid < 16384) {  // wcP: [32 k-octs][512 q] of virtual WC[256][512]
      int ko = gid >> 9, q = gid & 511;
      float v[8];
      #pragma unroll
      for (int j = 0; j < 8; ++j) {
        int dd = 8 * ko + j;
        float val;
        if (dd < 128) {
          val = (q < 384) ? rw.Wih[q * 128 + dd] : 0.f;
        } else {
          int dh = dd - 128;
          if (q < 256)      val = rw.Whh[q * 128 + dh];
          else if (q < 384) val = 0.f;
          else              val = rw.Whh[(q - 128) * 128 + dh];
        }
        v[j] = val;
      }
      wcP[gid] = make_uint4(packbf(v[0], v[1]), packbf(v[2], v[3]),
                            packbf(v[4], v[5]), packbf(v[6], v[7]));
    }
    if (gid < 8192) {  // m1P: [16 k-octs][512 q]
      int ko = gid >> 9, q = gid & 511;
      const float* src = &rw.mW1[q * 128 + 8 * ko];
      m1P[gid] = make_uint4(packbf(src[0], src[1]), packbf(src[2], src[3]),
                            packbf(src[4], src[5]), packbf(src[6], src[7]));
    }
    if (gid < 8192) {  // m2P: [64 k-octs][128 d]
      int ko = gid >> 7, d = gid & 127;
      const float* src = &rw.mW2[d * 512 + 8 * ko];
      m2P[gid] = make_uint4(packbf(src[0], src[1]), packbf(src[2], src[3]),
                            packbf(src[4], src[5]), packbf(src[6], src[7]));
    }
    if (gid < 2048) {  // wqP: [16 k-octs][128 o]
      int ko = gid >> 7, o = gid & 127;
      const float* src = &rw.Wq[o * 128 + 8 * ko];
      wqP[gid] = make_uint4(packbf(src[0], src[1]), packbf(src[2], src[3]),
                            packbf(src[4], src[5]), packbf(src[6], src[7]));
    }
  }
}

// ---------- pK: token pass per step (1024 threads, bf16 K/V in LDS) ----------
__global__ __launch_bounds__(1024, 1) void pK(const unsigned* __restrict__ kb,
    const unsigned* __restrict__ vb, const float* __restrict__ wcoef,
    const float* __restrict__ cbuf, float* __restrict__ part,
    float* __restrict__ attnu, int last) {
  __shared__ __align__(16) unsigned buf[64 * 68];   // K then V: [j][64 d-pair uints, pad 68]
  __shared__ __align__(16) float a1s[16 * 68];
  __shared__ float esum[16 * 64];
  int tid = threadIdx.x;
  int jt = blockIdx.x, b = blockIdx.y;
  size_t jrow = (size_t)(b * N_ + jt * 64);
  {
    int row = tid >> 4, oct = tid & 15;
    uint4 kv = *(const uint4*)&kb[(jrow + row) * 64 + oct * 4];
    *(uint4*)&buf[row * 68 + oct * 4] = kv;
  }
  __syncthreads();
  uint4 vr;
  {
    int row = tid >> 4, oct = tid & 15;
    vr = *(const uint4*)&vb[(jrow + row) * 64 + oct * 4];
  }
  // phase A: wave w owns slot w; lanes = tokens
  {
    int l = tid & 63;
    int w = __builtin_amdgcn_readfirstlane(threadIdx.x >> 6);
    const float4* wq4 = (const float4*)&wcoef[((size_t)b * 16 + w) * 256];
    float c0 = cbuf[b * NS_ + w];
    const uint4* kr = (const uint4*)&buf[l * 68];
    float a0 = 0.f, a1 = 0.f, a2 = 0.f, a3 = 0.f;
    #pragma unroll 8
    for (int i = 0; i < 16; ++i) {
      uint4 kv = kr[i];
      float4 wA = wq4[4 * i], wB = wq4[4 * i + 1], wC = wq4[4 * i + 2], wD = wq4[4 * i + 3];
      float k0 = bf_lo(kv.x), k1 = bf_hi(kv.x);
      float k2 = bf_lo(kv.y), k3 = bf_hi(kv.y);
      float k4 = bf_lo(kv.z), k5 = bf_hi(kv.z);
      float k6 = bf_lo(kv.w), k7 = bf_hi(kv.w);
      a0 = fmaf(fmaf(wA.y, k0, wA.x), k0, a0);
      a1 = fmaf(fmaf(wA.w, k1, wA.z), k1, a1);
      a2 = fmaf(fmaf(wB.y, k2, wB.x), k2, a2);
      a3 = fmaf(fmaf(wB.w, k3, wB.z), k3, a3);
      a0 = fmaf(fmaf(wC.y, k4, wC.x), k4, a0);
      a1 = fmaf(fmaf(wC.w, k5, wC.z), k5, a1);
      a2 = fmaf(fmaf(wD.y, k6, wD.x), k6, a2);
      a3 = fmaf(fmaf(wD.w, k7, wD.z), k7, a3);
    }
    float e0 = expf(-(c0 + (a0 + a1) + (a2 + a3))) + EPS_;
    esum[w * 64 + l] = e0;
    __syncthreads();
    float tot = 0.f;
    #pragma unroll
    for (int q = 0; q < 16; ++q) tot += esum[q * 64 + l];
    float av = e0 / tot;
    a1s[w * 68 + l] = av;
    if (last) attnu[(size_t)(b * NS_ + w) * N_ + jt * 64 + l] = av;
  }
  __syncthreads();
  {
    int row = tid >> 4, oct = tid & 15;
    *(uint4*)&buf[row * 68 + oct * 4] = vr;
  }
  __syncthreads();
  // phase B: wave ii owns slot ii; lane (l&31) owns d-quad; j split across lane halves
  {
    int ii = __builtin_amdgcn_readfirstlane(threadIdx.x >> 6);
    int lh = (tid >> 5) & 1;
    int dp = tid & 31;
    float av0 = 0, av1 = 0, av2 = 0, av3 = 0, aw0 = 0, aw1 = 0, aw2 = 0, aw3 = 0, rsum = 0;
    #pragma unroll
    for (int jj = 0; jj < 32; jj += 4) {
      int j = lh * 32 + jj;
      float4 a4 = *(const float4*)&a1s[ii * 68 + j];
      float aarr[4] = {a4.x, a4.y, a4.z, a4.w};
      #pragma unroll
      for (int e = 0; e < 4; ++e) {
        float a = aarr[e];
        uint2 q = *(const uint2*)&buf[(j + e) * 68 + dp * 2];
        float v0 = bf_lo(q.x), v1 = bf_hi(q.x), v2 = bf_lo(q.y), v3 = bf_hi(q.y);
        rsum += a;
        float m0 = a * v0, m1 = a * v1, m2 = a * v2, m3 = a * v3;
        av0 += m0; av1 += m1; av2 += m2; av3 += m3;
        aw0 = fmaf(m0, v0, aw0); aw1 = fmaf(m1, v1, aw1);
        aw2 = fmaf(m2, v2, aw2); aw3 = fmaf(m3, v3, aw3);
      }
    }
    av0 += __shfl_down(av0, 32, 64); av1 += __shfl_down(av1, 32, 64);
    av2 += __shfl_down(av2, 32, 64); av3 += __shfl_down(av3, 32, 64);
    aw0 += __shfl_down(aw0, 32, 64); aw1 += __shfl_down(aw1, 32, 64);
    aw2 += __shfl_down(aw2, 32, 64); aw3 += __shfl_down(aw3, 32, 64);
    rsum += __shfl_down(rsum, 32, 64);
    if ((tid & 63) < 32) {
      float* pr = &part[((size_t)(b * NT_ + jt) * NS_ + ii) * 260];
      *(float4*)&pr[dp * 4] = make_float4(av0, av1, av2, av3);
      *(float4*)&pr[128 + dp * 4] = make_float4(aw0, aw1, aw2, aw3);
      if ((tid & 63) == 0) pr[256] = rsum;
    }
  }
}

// ---------- rK: per-slot update (steps 0..2), 64 blocks x 1024 ----------
__global__ __launch_bounds__(1024, 1) void rK(const float* __restrict__ part,
    float* mu, float* wcoef, float* cbuf, SW w) {
  __shared__ __align__(16) float sl[S_TOT];
  int tid = threadIdx.x;
  int b = blockIdx.x >> 4, i = blockIdx.x & 15;
  slotUpdateT<0>(sl, b, i, tid, part, mu, wcoef, cbuf, w);
}

// ---------- oK: final slot update + out MLP (0..63) + attn normalize (64..127) ----------
__global__ __launch_bounds__(1024, 1) void oK(const float* __restrict__ part,
    float* mu, SW w,
    const unsigned* __restrict__ o1P, const float* __restrict__ ob1,
    const unsigned* __restrict__ o2P, const float* __restrict__ ob2,
    const float* __restrict__ attnu, float* __restrict__ out) {
  __shared__ __align__(16) float sl[S_TOT];
  int blk = blockIdx.x, tid = threadIdx.x;
  const size_t pstr = (size_t)NS_ * 260;
  if (blk >= 64) {
    int r = blk - 64;
    int b = r >> 4, i = r & 15;
    size_t pbase = ((size_t)(b * NT_) * NS_ + i) * 260;
    if (tid < 64) {
      float v = waveRed1(part[pbase + (size_t)tid * pstr + 256]);
      if (tid == 0) sl[0] = v;
    }
    __syncthreads();
    float rs = sl[0];
    int base = r * 4096 + tid * 4;
    float4 v = *(const float4*)&attnu[base];
    v.x /= rs; v.y /= rs; v.z /= rs; v.w /= rs;
    *(float4*)&out[8192 + base] = v;
    return;
  }
  int b = blk >> 4, i = blk & 15;
  slotUpdateT<1>(sl, b, i, tid, part, mu, (float*)nullptr, (float*)nullptr, w);
  // out-MLP up: 1024 outputs, 1/thread, octo-packed; h1 -> S_P1
  {
    const float* sn = sl + S_SNEW;
    const uint4* o1 = (const uint4*)o1P;
    float a0 = 0.f, a1 = 0.f, a2 = 0.f, a3 = 0.f;
    #pragma unroll 8
    for (int r = 0; r < 16; ++r) {
      oct_fma(o1[r * 1024 + tid], sn + 8 * r, a0, a1, a2, a3);
      oct_fma(o1[(16 + r) * 1024 + tid], sn + 128 + 8 * r, a0, a1, a2, a3);
    }
    sl[S_P1 + tid] = fmaxf((a0 + a1) + (a2 + a3) + ob1[tid], 0.f);
  }
  __syncthreads();
  // out-MLP down: 128 outputs, 8-way K-split, octo-packed
  float dpart = 0.f;
  {
    int d = tid & 127, qg = tid >> 7;
    const uint4* wc2 = (const uint4*)o2P + (size_t)(qg * 16) * 128 + d;
    const float* h = sl + S_P1 + qg * 128;
    float b0 = 0.f, b1 = 0.f, b2 = 0.f, b3 = 0.f;
    #pragma unroll 8
    for (int r = 0; r < 16; ++r)
      oct_fma(wc2[r * 128], h + 8 * r, b0, b1, b2, b3);
    dpart = (b0 + b1) + (b2 + b3);
  }
  __syncthreads();
  {
    int d = tid & 127, qg = tid >> 7;
    sl[qg * 128 + d] = dpart;
  }
  __syncthreads();
  if (tid < 128) {
    float o = ob2[tid];
    #pragma unroll
    for (int g = 0; g < 8; ++g) o += sl[g * 128 + tid];
    out[(size_t)blk * 128 + tid] = o;
  }
}

extern "C" void kernel_launch(void* const* d_in, const int* in_sizes, int n_in,
                              void* d_out, int out_size, void* d_ws, size_t ws_size,
                              hipStream_t stream) {
  const float* slots_in = (const float*)d_in[0];
  const float* inputs   = (const float*)d_in[1];
  const float* Wq  = (const float*)d_in[2];
  const float* Wk  = (const float*)d_in[3];
  const float* Wv  = (const float*)d_in[4];
  const float* Wih = (const float*)d_in[5];
  const float* Whh = (const float*)d_in[6];
  const float* bih = (const float*)d_in[7];
  const float* bhh = (const float*)d_in[8];
  const float* mW1 = (const float*)d_in[9];
  const float* mb1 = (const float*)d_in[10];
  const float* mW2 = (const float*)d_in[11];
  const float* mb2 = (const float*)d_in[12];
  const float* g_in  = (const float*)d_in[13];
  const float* be_in = (const float*)d_in[14];
  const float* g_sl  = (const float*)d_in[15];
  const float* be_sl = (const float*)d_in[16];
  const float* g_mu  = (const float*)d_in[17];
  const float* be_mu = (const float*)d_in[18];
  const float* oW1 = (const float*)d_in[19];
  const float* ob1 = (const float*)d_in[20];
  const float* oW2 = (const float*)d_in[21];
  const float* ob2 = (const float*)d_in[22];
  float* ws  = (float*)d_ws;
  float* out = (float*)d_out;
  (void)in_sizes; (void)n_in; (void)out_size; (void)ws_size;

  SW w;
  w.wcP = (const unsigned*)(ws + OFF_WCP);
  w.m1P = (const unsigned*)(ws + OFF_M1P);
  w.m2P = (const unsigned*)(ws + OFF_M2P);
  w.wqP = (const unsigned*)(ws + OFF_WQP);
  w.bih = bih; w.bhh = bhh; w.mb1 = mb1; w.mb2 = mb2;
  w.gmu = g_mu; w.bmu = be_mu; w.gsl = g_sl; w.bsl = be_sl;
  RW rw;
  rw.Wq = Wq; rw.Wih = Wih; rw.Whh = Whh;
  rw.mW1 = mW1; rw.mW2 = mW2; rw.oW1 = oW1; rw.oW2 = oW2;

  hipLaunchKernelGGL(tK, dim3(16), dim3(256), 0, stream,
                     Wk, Wv, (uint4*)(ws + OFF_WTF));
  hipLaunchKernelGGL(kvK, dim3(384), dim3(1024), 0, stream,
                     inputs, (const uint4*)(ws + OFF_WTF), g_in, be_in, slots_in, w, rw,
                     (unsigned*)(ws + OFF_K), (unsigned*)(ws + OFF_V),
                     ws + OFF_MU, ws + OFF_WCOEF, ws + OFF_C, ws);
  for (int s = 0; s < 4; ++s) {
    hipLaunchKernelGGL(pK, dim3(64, 4), dim3(1024), 0, stream,
                       (const unsigned*)(ws + OFF_K), (const unsigned*)(ws + OFF_V),
                       ws + OFF_WCOEF, ws + OFF_C,
                       ws + OFF_PART, ws + OFF_ATTNU, (s == 3) ? 1 : 0);
    if (s < 3) {
      hipLaunchKernelGGL(rK, dim3(64), dim3(1024), 0, stream,
                         ws + OFF_PART, ws + OFF_MU, ws + OFF_WCOEF, ws + OFF_C, w);
    }
  }
  hipLaunchKernelGGL(oK, dim3(128), dim3(1024), 0, stream,
                     ws + OFF_PART, ws + OFF_MU, w,
                     (const unsigned*)(ws + OFF_O1P), ob1,
                     (const unsigned*)(ws + OFF_O2P), ob2, ws + OFF_ATTNU, out);
}